// Round 18
// baseline (529.849 us; speedup 1.0000x reference)
//
#include <hip/hip_runtime.h>

#define NN 14541
#define RR 64
#define EE 16384
#define EMAX (RR * EE)
#define RN (RR * NN)              // 930624
#define NT 64
#define TILES 228                 // ceil(NN/64)
#define RGROUPS 8
#define RPG 8
#define NBPT 58                   // bins per thread in csr path (58*256 = 14848 >= NN+1)
#define NWORDS (NBPT * 256 / 2)   // 7424 packed words

typedef unsigned short u16;
typedef __attribute__((ext_vector_type(8))) short bf16x8;
typedef __attribute__((ext_vector_type(4))) float f32x4;

__device__ __forceinline__ u16 f2b(float f) {
  unsigned u = __builtin_bit_cast(unsigned, f);
  u += 0x7fffu + ((u >> 16) & 1u);
  return (u16)(u >> 16);
}
__device__ __forceinline__ float b2f(short h) {
  unsigned u = ((unsigned)(u16)h) << 16;
  return __builtin_bit_cast(float, u);
}
__device__ __forceinline__ unsigned cvtpk(float lo, float hi) {
  unsigned r;
  asm("v_cvt_pk_bf16_f32 %0, %1, %2" : "=v"(r) : "v"(lo), "v"(hi));
  return r;
}
__device__ __forceinline__ float sigm(float x) { return 1.0f / (1.0f + expf(-x)); }

__device__ __forceinline__ void gload_lds16(const void* g, void* l) {
  __builtin_amdgcn_global_load_lds(
      (const __attribute__((address_space(1))) unsigned int*)g,
      (__attribute__((address_space(3))) unsigned int*)l, 16, 0, 0);
}

// ---------- fused build: blocks 0-63 = per-relation CSR counting sort;
//            blocks 64+  = W transpose / emb cast / biases / counter-zero ----------
__global__ __launch_bounds__(256) void build_k(
    const int* __restrict__ src, const int* __restrict__ dst,
    int* __restrict__ row_ptr, int* __restrict__ ssrc,
    float* __restrict__ scoef, float* __restrict__ tmpc,
    const float* __restrict__ W1, const float* __restrict__ W2,
    const float* __restrict__ b1, const float* __restrict__ b2,
    const float* __restrict__ emb,
    u16* __restrict__ W1T, u16* __restrict__ W2T,
    u16* __restrict__ emb_bf, float* __restrict__ mb1, float* __restrict__ mb2,
    int* __restrict__ cnt)
{
  __shared__ __align__(16) unsigned smem[NWORDS * 2];   // 59392 B (union with prep's T)
  __shared__ int wsum[4];
  const int b = blockIdx.x, t = threadIdx.x;

  if (b < 64) {
    unsigned* cd = smem;
    unsigned* cs = smem + NWORDS;
    const int r = b;
    const int ebase = r * EE;

    for (int i = t; i < NWORDS; i += 256) { cd[i] = 0; cs[i] = 0; }
    __syncthreads();
    for (int e = t; e < EE; e += 256) {
      int d = dst[ebase + e], s = src[ebase + e];
      atomicAdd(&cd[d >> 1], (d & 1) ? 0x10000u : 1u);
      atomicAdd(&cs[s >> 1], (s & 1) ? 0x10000u : 1u);
    }
    __syncthreads();
    for (int e = t; e < EE; e += 256) {
      int d = dst[ebase + e], s = src[ebase + e];
      int cdd = (cd[d >> 1] >> ((d & 1) * 16)) & 0xffff;
      int css = (cs[s >> 1] >> ((s & 1) * 16)) & 0xffff;
      tmpc[ebase + e] = rsqrtf((float)cdd) * rsqrtf((float)css) * 0.015625f;
    }
    const int base = t * (NBPT / 2);
    int tot = 0;
    #pragma unroll
    for (int j = 0; j < NBPT / 2; j++) {
      unsigned w = cd[base + j];
      tot += (int)(w & 0xffff) + (int)(w >> 16);
    }
    const int lane = t & 63, wv = t >> 6;
    int x = tot;
    #pragma unroll
    for (int o = 1; o < 64; o <<= 1) { int y = __shfl_up(x, o, 64); if (lane >= o) x += y; }
    if (lane == 63) wsum[wv] = x;
    __syncthreads();
    int runl = x - tot;
    #pragma unroll
    for (int j = 0; j < 3; j++) if (j < wv) runl += wsum[j];
    const int nb0 = t * NBPT;
    #pragma unroll
    for (int j = 0; j < NBPT / 2; j++) {
      unsigned w = cd[base + j];
      int c0 = (int)(w & 0xffff), c1 = (int)(w >> 16);
      int n0 = nb0 + 2 * j;
      if (n0 <= NN)     row_ptr[r * NN + n0]     = r * EE + runl;
      if (n0 + 1 <= NN) row_ptr[r * NN + n0 + 1] = r * EE + runl + c0;
      cd[base + j] = (unsigned)(runl | ((runl + c0) << 16));
      runl += c0 + c1;
    }
    __syncthreads();
    for (int e = t; e < EE; e += 256) {
      int d = dst[ebase + e], s = src[ebase + e];
      unsigned old = atomicAdd(&cd[d >> 1], (d & 1) ? 0x10000u : 1u);
      int slot = ebase + (int)((old >> ((d & 1) * 16)) & 0xffff);
      ssrc[slot] = s;
      scoef[slot] = tmpc[ebase + e];
    }
    return;
  }

  float (*T)[65] = (float(*)[65])smem;
  const int bb = b - 64;
  if (bb < 128) {                          // W1: block = (r, h-half)
    const int h = t & 63, kof = t >> 6;
    const int r = bb >> 1, hbase = (bb & 1) << 6;
    const float* Wr = W1 + (r << 14) + hbase;
    for (int k0 = 0; k0 < 128; k0 += 4) {
      int k = k0 + kof;
      T[k][h] = Wr[k * 128 + h];
    }
    __syncthreads();
    u16* dstp = W1T + (r << 14) + hbase * 128;
    #pragma unroll
    for (int it = 0; it < 4; ++it) {
      int p = it * 256 + t;
      int hh = p >> 4, v = p & 15;
      int hg = hbase + hh;
      bf16x8 o;
      #pragma unroll
      for (int j = 0; j < 8; j++)
        o[j] = (short)f2b(T[((v ^ (hg & 7)) << 3) + j][hh]);
      *(bf16x8*)(dstp + hh * 128 + v * 8) = o;
    }
  } else if (bb < 192) {                   // W2: block = r
    const int h = t & 63, kof = t >> 6;
    const int r = bb - 128;
    const float* Wr = W2 + (r << 13);
    for (int k0 = 0; k0 < 128; k0 += 4) {
      int k = k0 + kof;
      T[k][h] = Wr[k * 64 + h];
    }
    __syncthreads();
    u16* dstp = W2T + (r << 13);
    #pragma unroll
    for (int it = 0; it < 4; ++it) {
      int p = it * 256 + t;
      int hh = p >> 4, v = p & 15;
      bf16x8 o;
      #pragma unroll
      for (int j = 0; j < 8; j++)
        o[j] = (short)f2b(T[((v ^ (hh & 7)) << 3) + j][hh]);
      *(bf16x8*)(dstp + hh * 128 + v * 8) = o;
    }
  } else if (bb < 2011) {                  // emb -> bf16, vectorized
    int i = ((bb - 192) * 256 + t) * 4;
    if (i < NN * 128) {
      float4 vv = *(const float4*)(emb + i);
      ushort4 o;
      o.x = f2b(vv.x); o.y = f2b(vv.y); o.z = f2b(vv.z); o.w = f2b(vv.w);
      *(ushort4*)(emb_bf + i) = o;
    }
  } else {                                 // mean biases + tile counters
    if (t < 128) { float s = 0.f; for (int r = 0; r < RR; r++) s += b1[r * 128 + t]; mb1[t] = s * (1.f/64.f); }
    if (t < 64)  { float s = 0.f; for (int r = 0; r < RR; r++) s += b2[r * 64 + t];  mb2[t] = s * (1.f/64.f); }
    for (int i = t; i < 512; i += 256) cnt[i] = 0;
  }
}

// ---------- conv1 + fused relu (last block of each tile reduces slices -> h1) ----------
__global__ __launch_bounds__(256, 2) void conv1_k(
    const u16* __restrict__ emb_bf, const int* __restrict__ row_ptr,
    const int* __restrict__ ssrc, const float* __restrict__ scoef,
    const u16* __restrict__ W1T, float* __restrict__ out1, int gstr,
    const float* __restrict__ mb1, u16* __restrict__ h1, int* __restrict__ cnt1)
{
  __shared__ __align__(16) u16 Bs[128 * 128];   // 32 KB (pre-swizzled W^T)
  __shared__ int lastf;

  const int tid = threadIdx.x;
  const int g = blockIdx.x & 7, t = blockIdx.x >> 3;
  const int nb = t * NT;
  const int lane = tid & 63, wid = tid >> 6, c15 = lane & 15, kg = lane >> 4;
  const int rq = lane >> 2, q = lane & 3;       // gather role: row rq, 16B-chunk q
  const int nq = nb + wid * 16 + rq;            // gather row (quad-uniform)
  const int srcl = c15 * 4 + kg;                // lane-transpose source
  const int gbase = g * RPG;

  f32x4 acc[8];
  #pragma unroll
  for (int b = 0; b < 8; b++) acc[b] = (f32x4){0.f, 0.f, 0.f, 0.f};

  int rc0 = row_ptr[gbase * NN + nq];
  int rc1 = row_ptr[gbase * NN + nq + 1];
  int ps[4]; float pc[4];
  {
    const int d0 = rc1 - rc0;
    #pragma unroll
    for (int m = 0; m < 4; m++) {
      ps[m] = 0; pc[m] = 0.f;
      if (m < d0) { ps[m] = ssrc[rc0 + m]; pc[m] = scoef[rc0 + m]; }
    }
  }

  for (int rr = 0; rr < RPG; ++rr) {
    const int r = gbase + rr;
    {
      const u16* src_g = W1T + (r << 14);
      #pragma unroll
      for (int it = 0; it < 8; ++it)
        gload_lds16(src_g + (it * 256 + tid) * 8, (u16*)Bs + (it * 256 + wid * 64) * 8);
    }
    int nr0 = 0, nr1 = 0;
    if (rr + 1 < RPG) { nr0 = row_ptr[(r + 1) * NN + nq]; nr1 = row_ptr[(r + 1) * NN + nq + 1]; }
    const int d = rc1 - rc0;
    float a[4][8];
    #pragma unroll
    for (int w = 0; w < 4; w++)
      #pragma unroll
      for (int j = 0; j < 8; j++) a[w][j] = 0.f;
    #pragma unroll
    for (int m = 0; m < 4; m++) {
      if (m < d) {
        const bf16x8* xr = (const bf16x8*)(emb_bf + (size_t)ps[m] * 128);
        #pragma unroll
        for (int w = 0; w < 4; w++) {
          bf16x8 v = xr[w * 4 + q];
          #pragma unroll
          for (int j = 0; j < 8; j++) a[w][j] = fmaf(pc[m], b2f(v[j]), a[w][j]);
        }
      }
    }
    for (int p = 4; __any(p < d); ++p) {
      if (p < d) {
        int sx = ssrc[rc0 + p];
        float c = scoef[rc0 + p];
        const bf16x8* xr = (const bf16x8*)(emb_bf + (size_t)sx * 128);
        #pragma unroll
        for (int w = 0; w < 4; w++) {
          bf16x8 v = xr[w * 4 + q];
          #pragma unroll
          for (int j = 0; j < 8; j++) a[w][j] = fmaf(c, b2f(v[j]), a[w][j]);
        }
      }
    }
    int qs[4]; float qc[4];
    {
      const int ndg = nr1 - nr0;
      #pragma unroll
      for (int m = 0; m < 4; m++) {
        qs[m] = 0; qc[m] = 0.f;
        if (m < ndg) { qs[m] = ssrc[nr0 + m]; qc[m] = scoef[nr0 + m]; }
      }
    }
    bf16x8 af[4];
    #pragma unroll
    for (int kk = 0; kk < 4; kk++) {
      unsigned w0 = cvtpk(a[kk][0], a[kk][1]);
      unsigned w1 = cvtpk(a[kk][2], a[kk][3]);
      unsigned w2 = cvtpk(a[kk][4], a[kk][5]);
      unsigned w3 = cvtpk(a[kk][6], a[kk][7]);
      uint4 uu;
      uu.x = (unsigned)__shfl((int)w0, srcl);
      uu.y = (unsigned)__shfl((int)w1, srcl);
      uu.z = (unsigned)__shfl((int)w2, srcl);
      uu.w = (unsigned)__shfl((int)w3, srcl);
      af[kk] = __builtin_bit_cast(bf16x8, uu);
    }
    __syncthreads();   // Bs DMA drained
    #pragma unroll
    for (int tc = 0; tc < 8; tc++) {
      const int hh = tc * 16 + c15;
      #pragma unroll
      for (int kk = 0; kk < 4; kk++) {
        int u = kk * 4 + kg;
        bf16x8 bfr = *(const bf16x8*)(Bs + hh * 128 + ((u ^ (hh & 7)) << 3));
        acc[tc] = __builtin_amdgcn_mfma_f32_16x16x32_bf16(af[kk], bfr, acc[tc], 0, 0, 0);
      }
    }
    rc0 = nr0; rc1 = nr1;
    #pragma unroll
    for (int m = 0; m < 4; m++) { ps[m] = qs[m]; pc[m] = qc[m]; }
    if (rr + 1 < RPG) __syncthreads();
  }
  // slice write
  {
    float* base = out1 + (size_t)g * gstr;
    #pragma unroll
    for (int qi = 0; qi < 4; qi++) {
      const int nn2 = nb + wid * 16 + kg * 4 + qi;
      if (nn2 < NN) {
        float* po = base + (size_t)nn2 * 128 + c15;
        if (gstr) {
          #pragma unroll
          for (int tc = 0; tc < 8; tc++) po[tc * 16] = acc[tc][qi];
        } else {
          #pragma unroll
          for (int tc = 0; tc < 8; tc++) atomicAdd(po + tc * 16, acc[tc][qi]);
        }
      }
    }
  }
  // fused relu: last finisher of this tile reduces the 8 slices -> h1
  __syncthreads();                      // all slice stores drained (vmcnt0)
  if (tid == 0) {
    __threadfence();                    // release: this block's lines -> coherent point
    int old = atomicAdd(&cnt1[t], 1);
    lastf = (old == RGROUPS - 1) ? 1 : 0;
    if (lastf) __threadfence();         // acquire: discard stale lines before reads
  }
  __syncthreads();
  if (lastf) {
    #pragma unroll
    for (int it = 0; it < 8; ++it) {
      int idx = it * 256 + tid;         // 2048 f32x4 covering 64 rows x 128 cols
      int row = idx >> 5, col4 = (idx & 31) * 4;
      int n = nb + row;
      if (n < NN) {
        size_t o = (size_t)n * 128 + col4;
        f32x4 v = *(const f32x4*)(mb1 + col4);
        if (gstr) {
          #pragma unroll
          for (int g2 = 0; g2 < RGROUPS; g2++)
            v += *(const f32x4*)(out1 + (size_t)g2 * gstr + o);
        } else {
          v += *(const f32x4*)(out1 + o);
        }
        ushort4 ov;
        ov.x = f2b(v.x > 0.f ? v.x : 0.f);
        ov.y = f2b(v.y > 0.f ? v.y : 0.f);
        ov.z = f2b(v.z > 0.f ? v.z : 0.f);
        ov.w = f2b(v.w > 0.f ? v.w : 0.f);
        *(ushort4*)(h1 + o) = ov;
      }
    }
  }
}

// ---------- conv2 + fused BiLSTM (last block of each tile runs LSTM for its 64 nodes) ----------
__global__ __launch_bounds__(256, 2) void conv2_k(
    const u16* __restrict__ h1, const int* __restrict__ row_ptr,
    const int* __restrict__ ssrc, const float* __restrict__ scoef,
    const u16* __restrict__ W2T, float* __restrict__ out2, int gstr,
    const float* __restrict__ mb2, const float* __restrict__ w_ih,
    const float* __restrict__ b_ih, const float* __restrict__ b_hh,
    float* __restrict__ outF, int* __restrict__ cnt2)
{
  __shared__ __align__(16) u16 Bs[2][64 * 128];    // 2 x 16 KB (reused as hs in tail)
  __shared__ int lastf;

  const int tid = threadIdx.x;
  const int g = blockIdx.x & 7, t = blockIdx.x >> 3;
  const int nb = t * NT;
  const int lane = tid & 63, wid = tid >> 6, c15 = lane & 15, kg = lane >> 4;
  const int rq = lane >> 2, q = lane & 3;
  const int nq = nb + wid * 16 + rq;
  const int srcl = c15 * 4 + kg;
  const int gbase = g * RPG;

  f32x4 acc[4];
  #pragma unroll
  for (int b = 0; b < 4; b++) acc[b] = (f32x4){0.f, 0.f, 0.f, 0.f};

  int rc0 = row_ptr[gbase * NN + nq];
  int rc1 = row_ptr[gbase * NN + nq + 1];
  int ps[4]; float pc[4];
  {
    const int d0 = rc1 - rc0;
    #pragma unroll
    for (int m = 0; m < 4; m++) {
      ps[m] = 0; pc[m] = 0.f;
      if (m < d0) { ps[m] = ssrc[rc0 + m]; pc[m] = scoef[rc0 + m]; }
    }
  }
  {
    const u16* src_g = W2T + (gbase << 13);
    #pragma unroll
    for (int it = 0; it < 4; ++it)
      gload_lds16(src_g + (it * 256 + tid) * 8, (u16*)Bs[0] + (it * 256 + wid * 64) * 8);
  }

  for (int rr = 0; rr < RPG; ++rr) {
    const int r = gbase + rr;
    if (rr + 1 < RPG) {
      const u16* src_g = W2T + ((r + 1) << 13);
      #pragma unroll
      for (int it = 0; it < 4; ++it)
        gload_lds16(src_g + (it * 256 + tid) * 8, (u16*)Bs[(rr + 1) & 1] + (it * 256 + wid * 64) * 8);
    }
    int nr0 = 0, nr1 = 0;
    if (rr + 1 < RPG) { nr0 = row_ptr[(r + 1) * NN + nq]; nr1 = row_ptr[(r + 1) * NN + nq + 1]; }
    const int d = rc1 - rc0;
    float a[4][8];
    #pragma unroll
    for (int w = 0; w < 4; w++)
      #pragma unroll
      for (int j = 0; j < 8; j++) a[w][j] = 0.f;
    #pragma unroll
    for (int m = 0; m < 4; m++) {
      if (m < d) {
        const bf16x8* xr = (const bf16x8*)(h1 + (size_t)ps[m] * 128);
        #pragma unroll
        for (int w = 0; w < 4; w++) {
          bf16x8 v = xr[w * 4 + q];
          #pragma unroll
          for (int j = 0; j < 8; j++) a[w][j] = fmaf(pc[m], b2f(v[j]), a[w][j]);
        }
      }
    }
    for (int p = 4; __any(p < d); ++p) {
      if (p < d) {
        int sx = ssrc[rc0 + p];
        float c = scoef[rc0 + p];
        const bf16x8* xr = (const bf16x8*)(h1 + (size_t)sx * 128);
        #pragma unroll
        for (int w = 0; w < 4; w++) {
          bf16x8 v = xr[w * 4 + q];
          #pragma unroll
          for (int j = 0; j < 8; j++) a[w][j] = fmaf(c, b2f(v[j]), a[w][j]);
        }
      }
    }
    int qs[4]; float qc[4];
    {
      const int ndg = nr1 - nr0;
      #pragma unroll
      for (int m = 0; m < 4; m++) {
        qs[m] = 0; qc[m] = 0.f;
        if (m < ndg) { qs[m] = ssrc[nr0 + m]; qc[m] = scoef[nr0 + m]; }
      }
    }
    bf16x8 af[4];
    #pragma unroll
    for (int kk = 0; kk < 4; kk++) {
      unsigned w0 = cvtpk(a[kk][0], a[kk][1]);
      unsigned w1 = cvtpk(a[kk][2], a[kk][3]);
      unsigned w2 = cvtpk(a[kk][4], a[kk][5]);
      unsigned w3 = cvtpk(a[kk][6], a[kk][7]);
      uint4 uu;
      uu.x = (unsigned)__shfl((int)w0, srcl);
      uu.y = (unsigned)__shfl((int)w1, srcl);
      uu.z = (unsigned)__shfl((int)w2, srcl);
      uu.w = (unsigned)__shfl((int)w3, srcl);
      af[kk] = __builtin_bit_cast(bf16x8, uu);
    }
    __syncthreads();
    const u16* Bcur = Bs[rr & 1];
    #pragma unroll
    for (int tc = 0; tc < 4; tc++) {
      const int hh = tc * 16 + c15;
      #pragma unroll
      for (int kk = 0; kk < 4; kk++) {
        int u = kk * 4 + kg;
        bf16x8 bfr = *(const bf16x8*)(Bcur + hh * 128 + ((u ^ (hh & 7)) << 3));
        acc[tc] = __builtin_amdgcn_mfma_f32_16x16x32_bf16(af[kk], bfr, acc[tc], 0, 0, 0);
      }
    }
    rc0 = nr0; rc1 = nr1;
    #pragma unroll
    for (int m = 0; m < 4; m++) { ps[m] = qs[m]; pc[m] = qc[m]; }
  }
  // slice write
  {
    float* base = out2 + (size_t)g * gstr;
    #pragma unroll
    for (int qi = 0; qi < 4; qi++) {
      const int nn2 = nb + wid * 16 + kg * 4 + qi;
      if (nn2 < NN) {
        float* po = base + (size_t)nn2 * 64 + c15;
        if (gstr) {
          #pragma unroll
          for (int tc = 0; tc < 4; tc++) po[tc * 16] = acc[tc][qi];
        } else {
          #pragma unroll
          for (int tc = 0; tc < 4; tc++) atomicAdd(po + tc * 16, acc[tc][qi]);
        }
      }
    }
  }
  // fused LSTM: last finisher of this tile runs gates for its 64 nodes
  __syncthreads();
  if (tid == 0) {
    __threadfence();
    int old = atomicAdd(&cnt2[t], 1);
    lastf = (old == RGROUPS - 1) ? 1 : 0;
    if (lastf) __threadfence();
  }
  __syncthreads();
  if (!lastf) return;

  float* hs = (float*)Bs;               // 64 x 64 f32 = 16 KB (Bs dead)
  #pragma unroll
  for (int it = 0; it < 16; ++it) {
    int idx = it * 256 + tid;           // 4096 = 64 rows x 64 cols
    int row = idx >> 6, k = idx & 63;
    int n = nb + row;
    float v = mb2[k];
    if (n < NN) {
      if (gstr) {
        #pragma unroll
        for (int g2 = 0; g2 < RGROUPS; g2++)
          v += out2[(size_t)g2 * gstr + (size_t)n * 64 + k];
      } else {
        v += out2[(size_t)n * 64 + k];
      }
    }
    hs[row * 64 + k] = v;
  }
  __syncthreads();
  const int k = tid & 63, sg = tid >> 6;     // thread: output k for 16 nodes
  const int dd = k >> 5, jj = k & 31;
  const float* wb = w_ih + dd * 128 * 64;
  const float bi = b_ih[dd * 128 + jj]      + b_hh[dd * 128 + jj];
  const float bg = b_ih[dd * 128 + 64 + jj] + b_hh[dd * 128 + 64 + jj];
  const float bo = b_ih[dd * 128 + 96 + jj] + b_hh[dd * 128 + 96 + jj];
  const float* wi = wb + jj * 64;
  const float* wg = wb + (64 + jj) * 64;
  const float* wo = wb + (96 + jj) * 64;
  float gi[16], gg[16], go[16];
  #pragma unroll
  for (int j = 0; j < 16; j++) { gi[j] = bi; gg[j] = bg; go[j] = bo; }
  #pragma unroll 4
  for (int kk = 0; kk < 64; kk++) {
    float w_i = wi[kk], w_g = wg[kk], w_o = wo[kk];
    const float* hrow = hs + (sg * 16) * 64 + kk;
    #pragma unroll
    for (int j = 0; j < 16; j++) {
      float hv = hrow[j * 64];
      gi[j] = fmaf(hv, w_i, gi[j]);
      gg[j] = fmaf(hv, w_g, gg[j]);
      go[j] = fmaf(hv, w_o, go[j]);
    }
  }
  #pragma unroll
  for (int j = 0; j < 16; j++) {
    int n = nb + sg * 16 + j;
    if (n < NN) {
      float c = sigm(gi[j]) * tanhf(gg[j]);
      outF[(size_t)n * 64 + k] = sigm(go[j]) * tanhf(c);
    }
  }
}

extern "C" void kernel_launch(void* const* d_in, const int* in_sizes, int n_in,
                              void* d_out, int out_size, void* d_ws, size_t ws_size,
                              hipStream_t stream) {
  const int*   src  = (const int*)d_in[1];
  const int*   dst  = (const int*)d_in[2];
  const float* emb  = (const float*)d_in[3];
  const float* W1   = (const float*)d_in[4];
  const float* b1   = (const float*)d_in[5];
  const float* W2   = (const float*)d_in[6];
  const float* b2   = (const float*)d_in[7];
  const float* w_ih = (const float*)d_in[8];
  const float* b_ih = (const float*)d_in[10];
  const float* b_hh = (const float*)d_in[11];
  float* out = (float*)d_out;

  char* ws = (char*)d_ws;
  size_t off = 0;
  float* out1f  = (float*)(ws + off); off += (size_t)NN * 128 * 4;   // fallback accumulators
  float* out2f  = (float*)(ws + off); off += (size_t)NN * 64 * 4;
  size_t zb_fb = off;                                // zeroed only in fallback mode
  int*   row_ptr= (int*)(ws + off);   off += (size_t)(RN + 256) * 4;
  int*   ssrc   = (int*)(ws + off);   off += (size_t)EMAX * 4;
  float* scoef  = (float*)(ws + off); off += (size_t)EMAX * 4;
  float* tmpc   = (float*)(ws + off); off += (size_t)EMAX * 4;
  u16*   emb_bf = (u16*)(ws + off);   off += (size_t)NN * 128 * 2;
  u16*   h1     = (u16*)(ws + off);   off += (size_t)NN * 128 * 2;
  u16*   W1T    = (u16*)(ws + off);   off += (size_t)RR * 128 * 128 * 2;
  u16*   W2T    = (u16*)(ws + off);   off += (size_t)RR * 64 * 128 * 2;
  float* mb1    = (float*)(ws + off); off += 512;
  float* mb2    = (float*)(ws + off); off += 256;
  int*   cnt    = (int*)(ws + off);   off += 512 * 4;   // cnt1 = cnt[0..255], cnt2 = cnt[256..]
  float* out1g  = (float*)(ws + off); off += (size_t)RGROUPS * NN * 128 * 4;  // slice mode
  float* out2g  = (float*)(ws + off); off += (size_t)RGROUPS * NN * 64 * 4;

  const bool slices = ws_size >= off;
  float* o1 = slices ? out1g : out1f;
  float* o2 = slices ? out2g : out2f;
  const int gs1 = slices ? NN * 128 : 0;
  const int gs2 = slices ? NN * 64 : 0;

  if (!slices) hipMemsetAsync(d_ws, 0, zb_fb, stream);
  build_k<<<64 + 2012, 256, 0, stream>>>(src, dst, row_ptr, ssrc, scoef, tmpc,
                                         W1, W2, b1, b2, emb, W1T, W2T, emb_bf, mb1, mb2, cnt);
  conv1_k<<<TILES * RGROUPS, 256, 0, stream>>>(emb_bf, row_ptr, ssrc, scoef, W1T, o1, gs1,
                                               mb1, h1, cnt);
  conv2_k<<<TILES * RGROUPS, 256, 0, stream>>>(h1, row_ptr, ssrc, scoef, W2T, o2, gs2,
                                               mb2, w_ih, b_ih, b_hh, out, cnt + 256);
}

// Round 19
// 308.484 us; speedup vs baseline: 1.7176x; 1.7176x over previous
//
#include <hip/hip_runtime.h>

#define NN 14541
#define RR 64
#define EE 16384
#define EMAX (RR * EE)
#define RN (RR * NN)              // 930624
#define NT 64
#define TILES 228                 // ceil(NN/64)
#define RGROUPS 8
#define RPG 8
#define NBPT 58                   // bins per thread in csr path (58*256 = 14848 >= NN+1)
#define NWORDS (NBPT * 256 / 2)   // 7424 packed words

typedef unsigned short u16;
typedef __attribute__((ext_vector_type(8))) short bf16x8;
typedef __attribute__((ext_vector_type(4))) float f32x4;

__device__ __forceinline__ u16 f2b(float f) {
  unsigned u = __builtin_bit_cast(unsigned, f);
  u += 0x7fffu + ((u >> 16) & 1u);
  return (u16)(u >> 16);
}
__device__ __forceinline__ float b2f(short h) {
  unsigned u = ((unsigned)(u16)h) << 16;
  return __builtin_bit_cast(float, u);
}
__device__ __forceinline__ unsigned cvtpk(float lo, float hi) {
  unsigned r;
  asm("v_cvt_pk_bf16_f32 %0, %1, %2" : "=v"(r) : "v"(lo), "v"(hi));
  return r;
}
__device__ __forceinline__ float sigm(float x) { return 1.0f / (1.0f + expf(-x)); }

__device__ __forceinline__ void gload_lds16(const void* g, void* l) {
  __builtin_amdgcn_global_load_lds(
      (const __attribute__((address_space(1))) unsigned int*)g,
      (__attribute__((address_space(3))) unsigned int*)l, 16, 0, 0);
}

// ---------- fused build: blocks 0-63 = per-relation CSR counting sort;
//            blocks 64+  = W transpose / emb cast / biases (independent work, one dispatch)
__global__ __launch_bounds__(256) void build_k(
    const int* __restrict__ src, const int* __restrict__ dst,
    int* __restrict__ row_ptr, int* __restrict__ ssrc,
    float* __restrict__ scoef, float* __restrict__ tmpc,
    const float* __restrict__ W1, const float* __restrict__ W2,
    const float* __restrict__ b1, const float* __restrict__ b2,
    const float* __restrict__ emb,
    u16* __restrict__ W1T, u16* __restrict__ W2T,
    u16* __restrict__ emb_bf, float* __restrict__ mb1, float* __restrict__ mb2)
{
  __shared__ __align__(16) unsigned smem[NWORDS * 2];   // 59392 B (union with prep's T)
  __shared__ int wsum[4];
  const int b = blockIdx.x, t = threadIdx.x;

  if (b < 64) {
    // ----- CSR path: one block per relation, all-LDS counting sort -----
    unsigned* cd = smem;            // dst counts -> cursors (2 u16 bins / word)
    unsigned* cs = smem + NWORDS;   // src counts
    const int r = b;
    const int ebase = r * EE;

    for (int i = t; i < NWORDS; i += 256) { cd[i] = 0; cs[i] = 0; }
    __syncthreads();
    for (int e = t; e < EE; e += 256) {
      int d = dst[ebase + e], s = src[ebase + e];
      atomicAdd(&cd[d >> 1], (d & 1) ? 0x10000u : 1u);
      atomicAdd(&cs[s >> 1], (s & 1) ? 0x10000u : 1u);
    }
    __syncthreads();
    for (int e = t; e < EE; e += 256) {
      int d = dst[ebase + e], s = src[ebase + e];
      int cdd = (cd[d >> 1] >> ((d & 1) * 16)) & 0xffff;
      int css = (cs[s >> 1] >> ((s & 1) * 16)) & 0xffff;
      tmpc[ebase + e] = rsqrtf((float)cdd) * rsqrtf((float)css) * 0.015625f;
    }
    const int base = t * (NBPT / 2);
    int tot = 0;
    #pragma unroll
    for (int j = 0; j < NBPT / 2; j++) {
      unsigned w = cd[base + j];
      tot += (int)(w & 0xffff) + (int)(w >> 16);
    }
    const int lane = t & 63, wv = t >> 6;
    int x = tot;
    #pragma unroll
    for (int o = 1; o < 64; o <<= 1) { int y = __shfl_up(x, o, 64); if (lane >= o) x += y; }
    if (lane == 63) wsum[wv] = x;
    __syncthreads();
    int runl = x - tot;
    #pragma unroll
    for (int j = 0; j < 3; j++) if (j < wv) runl += wsum[j];
    const int nb0 = t * NBPT;
    #pragma unroll
    for (int j = 0; j < NBPT / 2; j++) {
      unsigned w = cd[base + j];
      int c0 = (int)(w & 0xffff), c1 = (int)(w >> 16);
      int n0 = nb0 + 2 * j;
      if (n0 <= NN)     row_ptr[r * NN + n0]     = r * EE + runl;
      if (n0 + 1 <= NN) row_ptr[r * NN + n0 + 1] = r * EE + runl + c0;
      cd[base + j] = (unsigned)(runl | ((runl + c0) << 16));
      runl += c0 + c1;
    }
    __syncthreads();
    for (int e = t; e < EE; e += 256) {
      int d = dst[ebase + e], s = src[ebase + e];
      unsigned old = atomicAdd(&cd[d >> 1], (d & 1) ? 0x10000u : 1u);
      int slot = ebase + (int)((old >> ((d & 1) * 16)) & 0xffff);
      ssrc[slot] = s;
      scoef[slot] = tmpc[ebase + e];
    }
    return;
  }

  // ----- prep path -----
  float (*T)[65] = (float(*)[65])smem;    // 33280 B alias
  const int bb = b - 64;
  if (bb < 128) {                          // W1: block = (r, h-half)
    const int h = t & 63, kof = t >> 6;
    const int r = bb >> 1, hbase = (bb & 1) << 6;
    const float* Wr = W1 + (r << 14) + hbase;
    for (int k0 = 0; k0 < 128; k0 += 4) {
      int k = k0 + kof;
      T[k][h] = Wr[k * 128 + h];
    }
    __syncthreads();
    u16* dstp = W1T + (r << 14) + hbase * 128;
    #pragma unroll
    for (int it = 0; it < 4; ++it) {
      int p = it * 256 + t;
      int hh = p >> 4, v = p & 15;
      int hg = hbase + hh;
      bf16x8 o;
      #pragma unroll
      for (int j = 0; j < 8; j++)
        o[j] = (short)f2b(T[((v ^ (hg & 7)) << 3) + j][hh]);
      *(bf16x8*)(dstp + hh * 128 + v * 8) = o;
    }
  } else if (bb < 192) {                   // W2: block = r
    const int h = t & 63, kof = t >> 6;
    const int r = bb - 128;
    const float* Wr = W2 + (r << 13);
    for (int k0 = 0; k0 < 128; k0 += 4) {
      int k = k0 + kof;
      T[k][h] = Wr[k * 64 + h];
    }
    __syncthreads();
    u16* dstp = W2T + (r << 13);
    #pragma unroll
    for (int it = 0; it < 4; ++it) {
      int p = it * 256 + t;
      int hh = p >> 4, v = p & 15;
      bf16x8 o;
      #pragma unroll
      for (int j = 0; j < 8; j++)
        o[j] = (short)f2b(T[((v ^ (hh & 7)) << 3) + j][hh]);
      *(bf16x8*)(dstp + hh * 128 + v * 8) = o;
    }
  } else if (bb < 2011) {                  // emb -> bf16, vectorized
    int i = ((bb - 192) * 256 + t) * 4;
    if (i < NN * 128) {
      float4 vv = *(const float4*)(emb + i);
      ushort4 o;
      o.x = f2b(vv.x); o.y = f2b(vv.y); o.z = f2b(vv.z); o.w = f2b(vv.w);
      *(ushort4*)(emb_bf + i) = o;
    }
  } else {                                 // mean biases
    if (t < 128) { float s = 0.f; for (int r = 0; r < RR; r++) s += b1[r * 128 + t]; mb1[t] = s * (1.f/64.f); }
    if (t < 64)  { float s = 0.f; for (int r = 0; r < RR; r++) s += b2[r * 64 + t];  mb2[t] = s * (1.f/64.f); }
  }
}

// ---------- conv1: PAIR-staged B (2 relations per barrier pair; 8 barriers/block) ----------
__global__ __launch_bounds__(256, 2) void conv1_k(
    const u16* __restrict__ emb_bf, const int* __restrict__ row_ptr,
    const int* __restrict__ ssrc, const float* __restrict__ scoef,
    const u16* __restrict__ W1T, float* __restrict__ out1, int gstr)
{
  __shared__ __align__(16) u16 Bs[2][128 * 128];   // 64 KB (pre-swizzled W^T, 2 relations)

  const int tid = threadIdx.x;
  const int g = blockIdx.x & 7, t = blockIdx.x >> 3;
  const int nb = t * NT;
  const int lane = tid & 63, wid = tid >> 6, c15 = lane & 15, kg = lane >> 4;
  const int rq = lane >> 2, q = lane & 3;       // gather role: row rq, 16B-chunk q
  const int nq = nb + wid * 16 + rq;            // gather row (quad-uniform)
  const int srcl = c15 * 4 + kg;                // lane-transpose source
  const int gbase = g * RPG;

  f32x4 acc[8];
  #pragma unroll
  for (int b = 0; b < 8; b++) acc[b] = (f32x4){0.f, 0.f, 0.f, 0.f};

  for (int rr = 0; rr < RPG; rr += 2) {
    const int rA = gbase + rr, rB = rA + 1;
    // A. stage BOTH relations' B-tiles via DMA (16 x 16B per lane)
    {
      const u16* sgA = W1T + (rA << 14);
      const u16* sgB = W1T + (rB << 14);
      #pragma unroll
      for (int it = 0; it < 8; ++it) {
        gload_lds16(sgA + (it * 256 + tid) * 8, (u16*)Bs[0] + (it * 256 + wid * 64) * 8);
        gload_lds16(sgB + (it * 256 + tid) * 8, (u16*)Bs[1] + (it * 256 + wid * 64) * 8);
      }
    }
    // B. both relations' CSR meta (independent chains, issued together)
    int a0 = row_ptr[rA * NN + nq], a1 = row_ptr[rA * NN + nq + 1];
    int b0 = row_ptr[rB * NN + nq], b1 = row_ptr[rB * NN + nq + 1];
    const int dA = a1 - a0, dB = b1 - b0;
    int psA[4], psB[4]; float pcA[4], pcB[4];
    #pragma unroll
    for (int m = 0; m < 4; m++) {
      psA[m] = 0; pcA[m] = 0.f;
      if (m < dA) { psA[m] = ssrc[a0 + m]; pcA[m] = scoef[a0 + m]; }
      psB[m] = 0; pcB[m] = 0.f;
      if (m < dB) { psB[m] = ssrc[b0 + m]; pcB[m] = scoef[b0 + m]; }
    }
    // C. gather + pack relation A
    float aa[4][8];
    #pragma unroll
    for (int w = 0; w < 4; w++)
      #pragma unroll
      for (int j = 0; j < 8; j++) aa[w][j] = 0.f;
    #pragma unroll
    for (int m = 0; m < 4; m++) {
      if (m < dA) {
        const bf16x8* xr = (const bf16x8*)(emb_bf + (size_t)psA[m] * 128);
        #pragma unroll
        for (int w = 0; w < 4; w++) {
          bf16x8 v = xr[w * 4 + q];            // quad lanes -> 64B contiguous
          #pragma unroll
          for (int j = 0; j < 8; j++) aa[w][j] = fmaf(pcA[m], b2f(v[j]), aa[w][j]);
        }
      }
    }
    for (int p = 4; __any(p < dA); ++p) {
      if (p < dA) {
        int sx = ssrc[a0 + p]; float c = scoef[a0 + p];
        const bf16x8* xr = (const bf16x8*)(emb_bf + (size_t)sx * 128);
        #pragma unroll
        for (int w = 0; w < 4; w++) {
          bf16x8 v = xr[w * 4 + q];
          #pragma unroll
          for (int j = 0; j < 8; j++) aa[w][j] = fmaf(c, b2f(v[j]), aa[w][j]);
        }
      }
    }
    bf16x8 afA[4];
    #pragma unroll
    for (int kk = 0; kk < 4; kk++) {
      unsigned w0 = cvtpk(aa[kk][0], aa[kk][1]);
      unsigned w1 = cvtpk(aa[kk][2], aa[kk][3]);
      unsigned w2 = cvtpk(aa[kk][4], aa[kk][5]);
      unsigned w3 = cvtpk(aa[kk][6], aa[kk][7]);
      uint4 uu;
      uu.x = (unsigned)__shfl((int)w0, srcl);
      uu.y = (unsigned)__shfl((int)w1, srcl);
      uu.z = (unsigned)__shfl((int)w2, srcl);
      uu.w = (unsigned)__shfl((int)w3, srcl);
      afA[kk] = __builtin_bit_cast(bf16x8, uu);
    }
    // D. gather + pack relation B (reuses aa)
    #pragma unroll
    for (int w = 0; w < 4; w++)
      #pragma unroll
      for (int j = 0; j < 8; j++) aa[w][j] = 0.f;
    #pragma unroll
    for (int m = 0; m < 4; m++) {
      if (m < dB) {
        const bf16x8* xr = (const bf16x8*)(emb_bf + (size_t)psB[m] * 128);
        #pragma unroll
        for (int w = 0; w < 4; w++) {
          bf16x8 v = xr[w * 4 + q];
          #pragma unroll
          for (int j = 0; j < 8; j++) aa[w][j] = fmaf(pcB[m], b2f(v[j]), aa[w][j]);
        }
      }
    }
    for (int p = 4; __any(p < dB); ++p) {
      if (p < dB) {
        int sx = ssrc[b0 + p]; float c = scoef[b0 + p];
        const bf16x8* xr = (const bf16x8*)(emb_bf + (size_t)sx * 128);
        #pragma unroll
        for (int w = 0; w < 4; w++) {
          bf16x8 v = xr[w * 4 + q];
          #pragma unroll
          for (int j = 0; j < 8; j++) aa[w][j] = fmaf(c, b2f(v[j]), aa[w][j]);
        }
      }
    }
    bf16x8 afB[4];
    #pragma unroll
    for (int kk = 0; kk < 4; kk++) {
      unsigned w0 = cvtpk(aa[kk][0], aa[kk][1]);
      unsigned w1 = cvtpk(aa[kk][2], aa[kk][3]);
      unsigned w2 = cvtpk(aa[kk][4], aa[kk][5]);
      unsigned w3 = cvtpk(aa[kk][6], aa[kk][7]);
      uint4 uu;
      uu.x = (unsigned)__shfl((int)w0, srcl);
      uu.y = (unsigned)__shfl((int)w1, srcl);
      uu.z = (unsigned)__shfl((int)w2, srcl);
      uu.w = (unsigned)__shfl((int)w3, srcl);
      afB[kk] = __builtin_bit_cast(bf16x8, uu);
    }
    __syncthreads();   // both B-tiles' DMA drained
    // E. MFMA: both relations, no barrier between
    #pragma unroll
    for (int tc = 0; tc < 8; tc++) {
      const int hh = tc * 16 + c15;
      #pragma unroll
      for (int kk = 0; kk < 4; kk++) {
        int u = kk * 4 + kg;
        bf16x8 bfr = *(const bf16x8*)(Bs[0] + hh * 128 + ((u ^ (hh & 7)) << 3));
        acc[tc] = __builtin_amdgcn_mfma_f32_16x16x32_bf16(afA[kk], bfr, acc[tc], 0, 0, 0);
      }
    }
    #pragma unroll
    for (int tc = 0; tc < 8; tc++) {
      const int hh = tc * 16 + c15;
      #pragma unroll
      for (int kk = 0; kk < 4; kk++) {
        int u = kk * 4 + kg;
        bf16x8 bfr = *(const bf16x8*)(Bs[1] + hh * 128 + ((u ^ (hh & 7)) << 3));
        acc[tc] = __builtin_amdgcn_mfma_f32_16x16x32_bf16(afB[kk], bfr, acc[tc], 0, 0, 0);
      }
    }
    if (rr + 2 < RPG) __syncthreads();   // all waves done reading before restage
  }
  float* base = out1 + (size_t)g * gstr;
  #pragma unroll
  for (int qi = 0; qi < 4; qi++) {
    const int nn2 = nb + wid * 16 + kg * 4 + qi;
    if (nn2 < NN) {
      float* po = base + (size_t)nn2 * 128 + c15;
      if (gstr) {
        #pragma unroll
        for (int tc = 0; tc < 8; tc++) po[tc * 16] = acc[tc][qi];
      } else {
        #pragma unroll
        for (int tc = 0; tc < 8; tc++) atomicAdd(po + tc * 16, acc[tc][qi]);
      }
    }
  }
}

// ---------- relu + bias -> bf16 (vectorized slice-sum, nt loads) ----------
__global__ void relu_k(const float* __restrict__ out1, const float* __restrict__ mb1,
                       u16* __restrict__ h1, int gstr) {
  int i = (blockIdx.x * 256 + threadIdx.x) * 4;
  if (i >= NN * 128) return;
  f32x4 v = *(const f32x4*)(mb1 + (i & 127));
  if (gstr) {
    #pragma unroll
    for (int g = 0; g < RGROUPS; g++)
      v += __builtin_nontemporal_load((const f32x4*)(out1 + (size_t)g * gstr + i));
  } else {
    v += *(const f32x4*)(out1 + i);
  }
  ushort4 o;
  o.x = f2b(v.x > 0.f ? v.x : 0.f);
  o.y = f2b(v.y > 0.f ? v.y : 0.f);
  o.z = f2b(v.z > 0.f ? v.z : 0.f);
  o.w = f2b(v.w > 0.f ? v.w : 0.f);
  *(ushort4*)(h1 + i) = o;
}

// ---------- conv2: 256 thr, double-buffered Bs, single barrier per iter (proven) ----------
__global__ __launch_bounds__(256, 2) void conv2_k(
    const u16* __restrict__ h1, const int* __restrict__ row_ptr,
    const int* __restrict__ ssrc, const float* __restrict__ scoef,
    const u16* __restrict__ W2T, float* __restrict__ out2, int gstr)
{
  __shared__ __align__(16) u16 Bs[2][64 * 128];    // 2 x 16 KB

  const int tid = threadIdx.x;
  const int g = blockIdx.x & 7, t = blockIdx.x >> 3;
  const int nb = t * NT;
  const int lane = tid & 63, wid = tid >> 6, c15 = lane & 15, kg = lane >> 4;
  const int rq = lane >> 2, q = lane & 3;
  const int nq = nb + wid * 16 + rq;
  const int srcl = c15 * 4 + kg;
  const int gbase = g * RPG;

  f32x4 acc[4];
  #pragma unroll
  for (int b = 0; b < 4; b++) acc[b] = (f32x4){0.f, 0.f, 0.f, 0.f};

  int rc0 = row_ptr[gbase * NN + nq];
  int rc1 = row_ptr[gbase * NN + nq + 1];
  int ps[4]; float pc[4];
  {
    const int d0 = rc1 - rc0;
    #pragma unroll
    for (int m = 0; m < 4; m++) {
      ps[m] = 0; pc[m] = 0.f;
      if (m < d0) { ps[m] = ssrc[rc0 + m]; pc[m] = scoef[rc0 + m]; }
    }
  }
  // prologue stage buf0
  {
    const u16* src_g = W2T + (gbase << 13);
    #pragma unroll
    for (int it = 0; it < 4; ++it)
      gload_lds16(src_g + (it * 256 + tid) * 8, (u16*)Bs[0] + (it * 256 + wid * 64) * 8);
  }

  for (int rr = 0; rr < RPG; ++rr) {
    const int r = gbase + rr;
    if (rr + 1 < RPG) {
      const u16* src_g = W2T + ((r + 1) << 13);
      #pragma unroll
      for (int it = 0; it < 4; ++it)
        gload_lds16(src_g + (it * 256 + tid) * 8, (u16*)Bs[(rr + 1) & 1] + (it * 256 + wid * 64) * 8);
    }
    int nr0 = 0, nr1 = 0;
    if (rr + 1 < RPG) { nr0 = row_ptr[(r + 1) * NN + nq]; nr1 = row_ptr[(r + 1) * NN + nq + 1]; }
    const int d = rc1 - rc0;
    float a[4][8];
    #pragma unroll
    for (int w = 0; w < 4; w++)
      #pragma unroll
      for (int j = 0; j < 8; j++) a[w][j] = 0.f;
    #pragma unroll
    for (int m = 0; m < 4; m++) {
      if (m < d) {
        const bf16x8* xr = (const bf16x8*)(h1 + (size_t)ps[m] * 128);
        #pragma unroll
        for (int w = 0; w < 4; w++) {
          bf16x8 v = xr[w * 4 + q];
          #pragma unroll
          for (int j = 0; j < 8; j++) a[w][j] = fmaf(pc[m], b2f(v[j]), a[w][j]);
        }
      }
    }
    for (int p = 4; __any(p < d); ++p) {
      if (p < d) {
        int sx = ssrc[rc0 + p];
        float c = scoef[rc0 + p];
        const bf16x8* xr = (const bf16x8*)(h1 + (size_t)sx * 128);
        #pragma unroll
        for (int w = 0; w < 4; w++) {
          bf16x8 v = xr[w * 4 + q];
          #pragma unroll
          for (int j = 0; j < 8; j++) a[w][j] = fmaf(c, b2f(v[j]), a[w][j]);
        }
      }
    }
    int qs[4]; float qc[4];
    {
      const int ndg = nr1 - nr0;
      #pragma unroll
      for (int m = 0; m < 4; m++) {
        qs[m] = 0; qc[m] = 0.f;
        if (m < ndg) { qs[m] = ssrc[nr0 + m]; qc[m] = scoef[nr0 + m]; }
      }
    }
    bf16x8 af[4];
    #pragma unroll
    for (int kk = 0; kk < 4; kk++) {
      unsigned w0 = cvtpk(a[kk][0], a[kk][1]);
      unsigned w1 = cvtpk(a[kk][2], a[kk][3]);
      unsigned w2 = cvtpk(a[kk][4], a[kk][5]);
      unsigned w3 = cvtpk(a[kk][6], a[kk][7]);
      uint4 uu;
      uu.x = (unsigned)__shfl((int)w0, srcl);
      uu.y = (unsigned)__shfl((int)w1, srcl);
      uu.z = (unsigned)__shfl((int)w2, srcl);
      uu.w = (unsigned)__shfl((int)w3, srcl);
      af[kk] = __builtin_bit_cast(bf16x8, uu);
    }
    __syncthreads();   // cur buf staged a full iter ago; readers synced
    const u16* Bcur = Bs[rr & 1];
    #pragma unroll
    for (int tc = 0; tc < 4; tc++) {
      const int hh = tc * 16 + c15;
      #pragma unroll
      for (int kk = 0; kk < 4; kk++) {
        int u = kk * 4 + kg;
        bf16x8 bfr = *(const bf16x8*)(Bcur + hh * 128 + ((u ^ (hh & 7)) << 3));
        acc[tc] = __builtin_amdgcn_mfma_f32_16x16x32_bf16(af[kk], bfr, acc[tc], 0, 0, 0);
      }
    }
    rc0 = nr0; rc1 = nr1;
    #pragma unroll
    for (int m = 0; m < 4; m++) { ps[m] = qs[m]; pc[m] = qc[m]; }
  }
  float* base = out2 + (size_t)g * gstr;
  #pragma unroll
  for (int qi = 0; qi < 4; qi++) {
    const int nn2 = nb + wid * 16 + kg * 4 + qi;
    if (nn2 < NN) {
      float* po = base + (size_t)nn2 * 64 + c15;
      if (gstr) {
        #pragma unroll
        for (int tc = 0; tc < 4; tc++) po[tc * 16] = acc[tc][qi];
      } else {
        #pragma unroll
        for (int tc = 0; tc < 4; tc++) atomicAdd(po + tc * 16, acc[tc][qi]);
      }
    }
  }
}

// ---------- BiLSTM: 16 nodes/block, 4x weight reuse ----------
__global__ __launch_bounds__(256) void lstm_k(const float* __restrict__ out2, const float* __restrict__ mb2,
                                              const float* __restrict__ w_ih, const float* __restrict__ b_ih,
                                              const float* __restrict__ b_hh, float* __restrict__ out,
                                              int gstr) {
  __shared__ float hs[16][64];
  const int tid = threadIdx.x, s = tid >> 6, k = tid & 63;
  const int nb = blockIdx.x * 16;
  #pragma unroll
  for (int j = 0; j < 4; j++) {
    int n = nb + s * 4 + j;
    if (n < NN) {
      float v = mb2[k];
      if (gstr) {
        #pragma unroll
        for (int g = 0; g < RGROUPS; g++)
          v += __builtin_nontemporal_load(out2 + (size_t)g * gstr + n * 64 + k);
      } else {
        v += out2[n * 64 + k];
      }
      hs[s * 4 + j][k] = v;
    }
  }
  __syncthreads();
  const int d = k >> 5, jj = k & 31;
  const float* wb = w_ih + d * 128 * 64;
  const float bi = b_ih[d * 128 + jj]      + b_hh[d * 128 + jj];
  const float bg = b_ih[d * 128 + 64 + jj] + b_hh[d * 128 + 64 + jj];
  const float bo = b_ih[d * 128 + 96 + jj] + b_hh[d * 128 + 96 + jj];
  const float* wi = wb + jj * 64;
  const float* wg = wb + (64 + jj) * 64;
  const float* wo = wb + (96 + jj) * 64;
  float gi[4] = {bi, bi, bi, bi}, gg[4] = {bg, bg, bg, bg}, go[4] = {bo, bo, bo, bo};
  #pragma unroll 8
  for (int kk = 0; kk < 64; kk++) {
    float w_i = wi[kk], w_g = wg[kk], w_o = wo[kk];
    #pragma unroll
    for (int j = 0; j < 4; j++) {
      float hv = hs[s * 4 + j][kk];
      gi[j] = fmaf(hv, w_i, gi[j]);
      gg[j] = fmaf(hv, w_g, gg[j]);
      go[j] = fmaf(hv, w_o, go[j]);
    }
  }
  #pragma unroll
  for (int j = 0; j < 4; j++) {
    int n = nb + s * 4 + j;
    if (n < NN) {
      float c = sigm(gi[j]) * tanhf(gg[j]);
      out[n * 64 + k] = sigm(go[j]) * tanhf(c);
    }
  }
}

extern "C" void kernel_launch(void* const* d_in, const int* in_sizes, int n_in,
                              void* d_out, int out_size, void* d_ws, size_t ws_size,
                              hipStream_t stream) {
  const int*   src  = (const int*)d_in[1];
  const int*   dst  = (const int*)d_in[2];
  const float* emb  = (const float*)d_in[3];
  const float* W1   = (const float*)d_in[4];
  const float* b1   = (const float*)d_in[5];
  const float* W2   = (const float*)d_in[6];
  const float* b2   = (const float*)d_in[7];
  const float* w_ih = (const float*)d_in[8];
  const float* b_ih = (const float*)d_in[10];
  const float* b_hh = (const float*)d_in[11];
  float* out = (float*)d_out;

  char* ws = (char*)d_ws;
  size_t off = 0;
  float* out1f  = (float*)(ws + off); off += (size_t)NN * 128 * 4;   // fallback accumulators
  float* out2f  = (float*)(ws + off); off += (size_t)NN * 64 * 4;
  size_t zb_fb = off;                                // zeroed only in fallback mode
  int*   row_ptr= (int*)(ws + off);   off += (size_t)(RN + 256) * 4;
  int*   ssrc   = (int*)(ws + off);   off += (size_t)EMAX * 4;
  float* scoef  = (float*)(ws + off); off += (size_t)EMAX * 4;
  float* tmpc   = (float*)(ws + off); off += (size_t)EMAX * 4;
  u16*   emb_bf = (u16*)(ws + off);   off += (size_t)NN * 128 * 2;
  u16*   h1     = (u16*)(ws + off);   off += (size_t)NN * 128 * 2;
  u16*   W1T    = (u16*)(ws + off);   off += (size_t)RR * 128 * 128 * 2;
  u16*   W2T    = (u16*)(ws + off);   off += (size_t)RR * 64 * 128 * 2;
  float* mb1    = (float*)(ws + off); off += 512;
  float* mb2    = (float*)(ws + off); off += 256;
  float* out1g  = (float*)(ws + off); off += (size_t)RGROUPS * NN * 128 * 4;  // slice mode
  float* out2g  = (float*)(ws + off); off += (size_t)RGROUPS * NN * 64 * 4;

  const bool slices = ws_size >= off;
  float* o1 = slices ? out1g : out1f;
  float* o2 = slices ? out2g : out2f;
  const int gs1 = slices ? NN * 128 : 0;
  const int gs2 = slices ? NN * 64 : 0;

  if (!slices) hipMemsetAsync(d_ws, 0, zb_fb, stream);
  build_k<<<64 + 2012, 256, 0, stream>>>(src, dst, row_ptr, ssrc, scoef, tmpc,
                                         W1, W2, b1, b2, emb, W1T, W2T, emb_bf, mb1, mb2);
  conv1_k<<<TILES * RGROUPS, 256, 0, stream>>>(emb_bf, row_ptr, ssrc, scoef, W1T, o1, gs1);
  relu_k<<<(NN * 128 / 4 + 255) / 256, 256, 0, stream>>>(o1, mb1, h1, gs1);
  conv2_k<<<TILES * RGROUPS, 256, 0, stream>>>(h1, row_ptr, ssrc, scoef, W2T, o2, gs2);
  lstm_k<<<(NN + 15) / 16, 256, 0, stream>>>(o2, mb2, w_ih, b_ih, b_hh, out, gs2);
}